// Round 1
// baseline (975.803 us; speedup 1.0000x reference)
//
#include <hip/hip_runtime.h>
#include <math.h>

// Problem constants (derived from reference): D=256 fixed; N, K from in_sizes.
#define D    256
#define D4   64      // float4 per row
#define TM   64      // token tile
#define TN   64      // codebook-entry tile
#define TD   64      // D chunk
#define KB   4       // K-dimension split across blocks

// ---------------------------------------------------------------------------
// k0: c2[k] = sum_d sub[k][d]^2 in f64; entries k >= K get +inf (masks padding
// from the argmin for free: inf score never wins under strict-< compare).
// One wave (64 lanes) per k; lane l covers float4 at d = 4*l.
__global__ __launch_bounds__(256)
void k0_c2(const float4* __restrict__ cb4, const int* __restrict__ ridx,
           double* __restrict__ c2, int K, int kpad) {
    int k    = (int)(blockIdx.x * (blockDim.x >> 6) + (threadIdx.x >> 6));
    int lane = threadIdx.x & 63;
    if (k >= kpad) return;
    double s = 0.0;
    if (k < K) {
        int row = ridx[k];
        float4 v = cb4[(size_t)row * D4 + lane];
        s = (double)v.x * v.x + (double)v.y * v.y
          + (double)v.z * v.z + (double)v.w * v.w;
    }
    #pragma unroll
    for (int off = 32; off; off >>= 1) s += __shfl_xor(s, off, 64);
    if (lane == 0) c2[k] = (k < K) ? s : (double)INFINITY;
}

// ---------------------------------------------------------------------------
// k1: for a 64-token tile and a K-range (kb), compute score = c2 - 2*(x.c)
// with f64 accumulation (exact products), track per-token running
// (min, argmin) with lexicographic tie-break (first index wins, matching
// jnp.argmin). Partial per-(token, kb) result -> ws.
__global__ __launch_bounds__(256)
void k1_argmin(const float4* __restrict__ x4, const float4* __restrict__ cb4,
               const int* __restrict__ ridx, const double* __restrict__ c2,
               double* __restrict__ pval, int* __restrict__ pidx,
               int Ntok, int K, int ktiles) {
    // Stage d-major so compute reads are contiguous float4 per lane.
    __shared__ __align__(16) float xs[TD][TM + 4];   // xs[d][m], stride 68 (16B-aligned rows)
    __shared__ __align__(16) float cs[TD][TN + 4];   // cs[d][n]
    __shared__ int    idx_t[TN];
    __shared__ double c2_t[TN];

    const int tid = threadIdx.x;
    const int r   = tid >> 4;   // token group 0..15 (4 tokens each)
    const int c   = tid & 15;   // entry group 0..15 (4 entries each)
    const int m0  = blockIdx.x * TM;
    const int kb  = blockIdx.y;
    const int kbase0 = kb * ktiles * TN;

    double bestv[4] = {INFINITY, INFINITY, INFINITY, INFINITY};
    int    besti[4] = {0, 0, 0, 0};

    for (int t = 0; t < ktiles; ++t) {
        const int kbase = kbase0 + t * TN;
        if (tid < TN) {
            int k  = kbase + tid;
            int kc = (k < K) ? k : 0;        // clamped row for padded entries
            idx_t[tid] = ridx[kc];
            c2_t[tid]  = c2[k];              // +inf for padded entries
        }
        __syncthreads();

        double acc[4][4] = {};
        const int lr = tid >> 4, lc = tid & 15;   // staging: row-in-16, float4 col
        #pragma unroll
        for (int ch = 0; ch < D / TD; ++ch) {
            #pragma unroll
            for (int p = 0; p < 4; ++p) {
                int m = p * 16 + lr;              // 0..63 (token row / entry row)
                float4 v = x4[(size_t)(m0 + m) * D4 + ch * (TD / 4) + lc];
                xs[4 * lc + 0][m] = v.x; xs[4 * lc + 1][m] = v.y;
                xs[4 * lc + 2][m] = v.z; xs[4 * lc + 3][m] = v.w;
                int row = idx_t[m];
                float4 w = cb4[(size_t)row * D4 + ch * (TD / 4) + lc];
                cs[4 * lc + 0][m] = w.x; cs[4 * lc + 1][m] = w.y;
                cs[4 * lc + 2][m] = w.z; cs[4 * lc + 3][m] = w.w;
            }
            __syncthreads();
            #pragma unroll 8
            for (int d = 0; d < TD; ++d) {
                const float4 xf = *reinterpret_cast<const float4*>(&xs[d][4 * r]);
                const float4 cf = *reinterpret_cast<const float4*>(&cs[d][4 * c]);
                const double xd[4] = {xf.x, xf.y, xf.z, xf.w};
                const double cd[4] = {cf.x, cf.y, cf.z, cf.w};
                #pragma unroll
                for (int i = 0; i < 4; ++i)
                    #pragma unroll
                    for (int j = 0; j < 4; ++j)
                        acc[i][j] = fma(xd[i], cd[j], acc[i][j]);
            }
            __syncthreads();
        }

        // Argmin update for this 64x64 tile.
        #pragma unroll
        for (int j = 0; j < 4; ++j) {
            const int    k  = kbase + 4 * c + j;
            const double cc = c2_t[4 * c + j];
            #pragma unroll
            for (int i = 0; i < 4; ++i) {
                double sc = cc - 2.0 * acc[i][j];
                if (sc < bestv[i] || (sc == bestv[i] && k < besti[i])) {
                    bestv[i] = sc; besti[i] = k;
                }
            }
        }
        __syncthreads();   // protect idx_t/c2_t rewrite next tile
    }

    // Reduce across the 16 entry-groups per token (alias xs/cs as scratch).
    double* rv = reinterpret_cast<double*>(xs);   // 64*16 doubles = 8 KiB <= xs
    int*    ri = reinterpret_cast<int*>(cs);      // 64*16 ints   = 4 KiB <= cs
    #pragma unroll
    for (int i = 0; i < 4; ++i) {
        int m = 4 * r + i;
        rv[m * 16 + c] = bestv[i];
        ri[m * 16 + c] = besti[i];
    }
    __syncthreads();
    if (tid < TM) {
        double bv = rv[tid * 16];
        int    bi = ri[tid * 16];
        #pragma unroll
        for (int cc = 1; cc < 16; ++cc) {
            double v  = rv[tid * 16 + cc];
            int    ii = ri[tid * 16 + cc];
            if (v < bv || (v == bv && ii < bi)) { bv = v; bi = ii; }
        }
        pval[(size_t)kb * Ntok + m0 + tid] = bv;
        pidx[(size_t)kb * Ntok + m0 + tid] = bi;
    }
}

// ---------------------------------------------------------------------------
// k2: combine KB partials per token, map local idx -> global codebook idx,
// gather codebook row to d_out, write index (as float), per-token sq-err sum.
// One wave per token.
__global__ __launch_bounds__(256)
void k2_gather(const float4* __restrict__ x4, const float4* __restrict__ cb4,
               const int* __restrict__ ridx,
               const double* __restrict__ pval, const int* __restrict__ pidx,
               float4* __restrict__ out_tok, float* __restrict__ out_idx,
               float* __restrict__ tok_loss, int Ntok) {
    int t    = (int)(blockIdx.x * (blockDim.x >> 6) + (threadIdx.x >> 6));
    int lane = threadIdx.x & 63;
    if (t >= Ntok) return;

    int g = 0;
    if (lane == 0) {
        double bv = INFINITY; int bi = 0x7fffffff;
        #pragma unroll
        for (int kb = 0; kb < KB; ++kb) {
            double v  = pval[(size_t)kb * Ntok + t];
            int    ii = pidx[(size_t)kb * Ntok + t];
            if (v < bv || (v == bv && ii < bi)) { bv = v; bi = ii; }
        }
        g = ridx[bi];
        out_idx[t] = (float)g;
    }
    g = __shfl(g, 0, 64);

    float4 cv = cb4[(size_t)g * D4 + lane];
    float4 xv = x4[(size_t)t * D4 + lane];
    out_tok[(size_t)t * D4 + lane] = cv;
    float dx = cv.x - xv.x, dy = cv.y - xv.y, dz = cv.z - xv.z, dw = cv.w - xv.w;
    float s = dx * dx + dy * dy + dz * dz + dw * dw;
    #pragma unroll
    for (int off = 32; off; off >>= 1) s += __shfl_xor(s, off, 64);
    if (lane == 0) tok_loss[t] = s;
}

// ---------------------------------------------------------------------------
// k3: deterministic fixed-order reduction of per-token loss sums -> mean.
__global__ __launch_bounds__(256)
void k3_loss(const float* __restrict__ tok_loss, float* __restrict__ out_loss,
             int Ntok, double inv_total) {
    __shared__ double sm[256];
    double s = 0.0;
    for (int i = threadIdx.x; i < Ntok; i += 256) s += (double)tok_loss[i];
    sm[threadIdx.x] = s;
    __syncthreads();
    for (int st = 128; st; st >>= 1) {
        if ((int)threadIdx.x < st) sm[threadIdx.x] += sm[threadIdx.x + st];
        __syncthreads();
    }
    if (threadIdx.x == 0) *out_loss = (float)(sm[0] * inv_total);
}

// ---------------------------------------------------------------------------
extern "C" void kernel_launch(void* const* d_in, const int* in_sizes, int n_in,
                              void* d_out, int out_size, void* d_ws, size_t ws_size,
                              hipStream_t stream) {
    const float* x    = (const float*)d_in[0];
    const float* cb   = (const float*)d_in[1];
    const int*   ridx = (const int*)d_in[2];

    const int Ntok = in_sizes[0] / D;                 // 16384
    const int K    = in_sizes[2];                     // 3686

    const int tiles_total = (K + TN - 1) / TN;        // 58
    const int ktiles      = (tiles_total + KB - 1) / KB;  // 15
    const int kpad        = KB * ktiles * TN;         // 3840

    float* out      = (float*)d_out;
    float* out_loss = out + (size_t)Ntok * D;
    float* out_idx  = out + (size_t)Ntok * D + 1;

    // ws layout (256B-aligned chunks)
    char* w = (char*)d_ws;
    double* c2 = (double*)w;   w += (((size_t)kpad * 8) + 255) & ~(size_t)255;
    double* pv = (double*)w;   w += (((size_t)KB * Ntok * 8) + 255) & ~(size_t)255;
    int*    pi = (int*)w;      w += (((size_t)KB * Ntok * 4) + 255) & ~(size_t)255;
    float*  tl = (float*)w;

    const float4* x4  = (const float4*)x;
    const float4* cb4 = (const float4*)cb;

    // k0: c2 (padded with +inf)
    k0_c2<<<dim3((kpad + 3) / 4), dim3(256), 0, stream>>>(cb4, ridx, c2, K, kpad);

    // k1: tiled distance + partial argmin
    dim3 g1(Ntok / TM, KB);
    k1_argmin<<<g1, dim3(256), 0, stream>>>(x4, cb4, ridx, c2, pv, pi, Ntok, K, ktiles);

    // k2: combine + gather + per-token loss
    k2_gather<<<dim3((Ntok + 3) / 4), dim3(256), 0, stream>>>(
        x4, cb4, ridx, pv, pi, (float4*)out, out_idx, tl, Ntok);

    // k3: loss mean
    k3_loss<<<dim3(1), dim3(256), 0, stream>>>(tl, out_loss, Ntok,
                                               1.0 / ((double)Ntok * (double)D));
}

// Round 2
// 636.848 us; speedup vs baseline: 1.5322x; 1.5322x over previous
//
#include <hip/hip_runtime.h>
#include <math.h>

// Problem geometry: D=256 fixed; N, K from in_sizes.
#define D      256
#define D4     64      // float4 per row
#define TM     128     // token tile
#define TN     128     // entry tile
#define KB     4       // K splits
#define KTILES 8       // tiles per split (ceil(29/4)); kpad = KB*KTILES*TN = 4096
#define TAU    6.0e-3f // margin threshold: worst-case f32 score error ~7.7e-4 -> 4x safety

// ---------------------------------------------------------------------------
// k0: c2[k] = ||sub_k||^2 (f64 internal, f32 out); padded entries -> +inf so
// they never win the argmin. One wave per k.
__global__ __launch_bounds__(256)
void k0_c2(const float4* __restrict__ cb4, const int* __restrict__ ridx,
           float* __restrict__ c2, int K, int kpad) {
    int k    = (int)(blockIdx.x * 4 + (threadIdx.x >> 6));
    int lane = threadIdx.x & 63;
    if (k >= kpad) return;
    double s = 0.0;
    if (k < K) {
        int row = ridx[k];
        float4 v = cb4[(size_t)row * D4 + lane];
        s = (double)v.x * v.x + (double)v.y * v.y
          + (double)v.z * v.z + (double)v.w * v.w;
    }
    #pragma unroll
    for (int off = 32; off; off >>= 1) s += __shfl_xor(s, off, 64);
    if (lane == 0) c2[k] = (k < K) ? (float)s : INFINITY;
}

// ---------------------------------------------------------------------------
// k1: f32 distance pass. 128x128 tile, 8x8 micro-tile, row-major LDS tiles
// with float4 XOR swizzle (phys_f4 = f ^ (row&7)): staging writes and compute
// reads are bank-conflict-free (<=2-way). Tracks per-token (best, 2nd-best,
// idx) per K-split for the margin-based exact recheck.
__global__ __launch_bounds__(256, 2)
void k1_argmin(const float4* __restrict__ x4, const float4* __restrict__ cb4,
               const int* __restrict__ ridx, const float* __restrict__ c2,
               float* __restrict__ pb1, float* __restrict__ pb2,
               int* __restrict__ pbi, int Ntok, int K, int kspan) {
    __shared__ float4 xs4[TM * 16];   // 32 KiB  [row][f^(row&7)]
    __shared__ float4 cs4[TN * 16];   // 32 KiB
    __shared__ float  c2_t[TN];

    const int tid = threadIdx.x;
    const int r   = tid >> 4;         // 0..15: token group (8 rows each)
    const int c   = tid & 15;         // 0..15: entry lane (rows c+16j)
    const int m0  = blockIdx.x * TM;
    const int kb  = blockIdx.y;
    const int kbase0 = kb * kspan;

    float b1[8], b2[8]; int bi[8];
    #pragma unroll
    for (int i = 0; i < 8; ++i) { b1[i] = INFINITY; b2[i] = INFINITY; bi[i] = 0; }

    for (int t = 0; t < KTILES; ++t) {
        const int kbase = kbase0 + t * TN;
        if (kbase >= K) break;                     // uniform per block (kb-dependent)
        __syncthreads();                           // LDS + c2_t reuse guard
        if (tid < TN) c2_t[tid] = c2[kbase + tid];
        int cidx[8];
        #pragma unroll
        for (int q = 0; q < 8; ++q) {
            int k = kbase + 16 * q + r;
            cidx[q] = ridx[(k < K) ? k : 0];       // clamped; c2=+inf masks pads
        }

        float acc[8][8];
        #pragma unroll
        for (int i = 0; i < 8; ++i)
            #pragma unroll
            for (int j = 0; j < 8; ++j) acc[i][j] = 0.f;

        for (int ch = 0; ch < 4; ++ch) {           // D chunks of 64
            __syncthreads();
            #pragma unroll
            for (int q = 0; q < 8; ++q) {          // conflict-free b128 staging
                int row = 16 * q + r;
                int p   = c ^ (row & 7);
                xs4[row * 16 + p] = x4[(size_t)(m0 + row) * D4 + ch * 16 + c];
                cs4[row * 16 + p] = cb4[(size_t)cidx[q] * D4 + ch * 16 + c];
            }
            __syncthreads();
            #pragma unroll 2
            for (int f = 0; f < 16; ++f) {
                float4 xf[8];
                #pragma unroll
                for (int i = 0; i < 8; ++i)        // broadcast reads (uniform addr)
                    xf[i] = xs4[(8 * r + i) * 16 + (f ^ i)];
                #pragma unroll
                for (int j = 0; j < 8; ++j) {      // 2-way reads (free)
                    float4 cf = cs4[(c + 16 * j) * 16 + (f ^ (c & 7))];
                    #pragma unroll
                    for (int i = 0; i < 8; ++i) {
                        acc[i][j] = fmaf(xf[i].x, cf.x, acc[i][j]);
                        acc[i][j] = fmaf(xf[i].y, cf.y, acc[i][j]);
                        acc[i][j] = fmaf(xf[i].z, cf.z, acc[i][j]);
                        acc[i][j] = fmaf(xf[i].w, cf.w, acc[i][j]);
                    }
                }
            }
        }
        // epilogue: score + top-2 update (ties land in b2 -> margin 0 -> flagged)
        #pragma unroll
        for (int j = 0; j < 8; ++j) {
            float c2v = c2_t[c + 16 * j];
            int   k   = kbase + c + 16 * j;
            #pragma unroll
            for (int i = 0; i < 8; ++i) {
                float sc = fmaf(-2.f, acc[i][j], c2v);
                if (sc < b1[i]) { b2[i] = b1[i]; b1[i] = sc; bi[i] = k; }
                else            { b2[i] = fminf(b2[i], sc); }
            }
        }
    }

    // cross-thread top-2 merge: 16 c-lanes per token row, via LDS scratch
    __syncthreads();
    float* s1 = (float*)xs4;          // 8 KiB
    float* s2 = s1 + TM * 16;         // 8 KiB
    int*   si = (int*)cs4;            // 8 KiB
    #pragma unroll
    for (int i = 0; i < 8; ++i) {
        int row = 8 * r + i;
        s1[row * 16 + c] = b1[i];
        s2[row * 16 + c] = b2[i];
        si[row * 16 + c] = bi[i];
    }
    __syncthreads();
    if (tid < TM) {
        float v1 = s1[tid * 16], v2 = s2[tid * 16];
        int   vi = si[tid * 16];
        #pragma unroll
        for (int cc = 1; cc < 16; ++cc) {
            float u1 = s1[tid * 16 + cc], u2 = s2[tid * 16 + cc];
            int   ui = si[tid * 16 + cc];
            if (u1 < v1 || (u1 == v1 && ui < vi)) { v2 = fminf(v1, u2); v1 = u1; vi = ui; }
            else                                  { v2 = fminf(v2, u1); }
        }
        size_t o = (size_t)kb * Ntok + m0 + tid;
        pb1[o] = v1; pb2[o] = v2; pbi[o] = vi;
    }
}

// ---------------------------------------------------------------------------
// k2: combine KB splits per token; write global codebook row; flag near-ties.
__global__ __launch_bounds__(256)
void k2_combine(const float* __restrict__ pb1, const float* __restrict__ pb2,
                const int* __restrict__ pbi, const int* __restrict__ ridx,
                int* __restrict__ gidx, int* __restrict__ tlist,
                int* __restrict__ cnt, int Ntok) {
    int t = blockIdx.x * 256 + threadIdx.x;
    if (t >= Ntok) return;
    float v1 = INFINITY, v2 = INFINITY; int vi = 0x7fffffff;
    #pragma unroll
    for (int kb = 0; kb < KB; ++kb) {
        size_t o = (size_t)kb * Ntok + t;
        float u1 = pb1[o], u2 = pb2[o]; int ui = pbi[o];
        if (u1 < v1 || (u1 == v1 && ui < vi)) { v2 = fminf(v1, u2); v1 = u1; vi = ui; }
        else                                  { v2 = fminf(v2, u1); }
    }
    gidx[t] = ridx[vi];
    if (v2 - v1 < TAU) {                      // near-tie: needs exact resolve
        int pos = atomicAdd(cnt, 1);
        tlist[pos] = t;
    }
}

// ---------------------------------------------------------------------------
// k_recheck: exact f64 argmin (self-contained: recomputes ||c||^2 too) with
// lexicographic tie-break for flagged tokens. One block per flagged token,
// grid-strided; per-token output write -> deterministic despite atomic order.
__global__ __launch_bounds__(256)
void k_recheck(const float4* __restrict__ x4, const float4* __restrict__ cb4,
               const int* __restrict__ ridx, const int* __restrict__ tlist,
               const int* __restrict__ cnt, int* __restrict__ gidx, int K) {
    __shared__ float4 xls[D4];
    __shared__ double rv[256];
    __shared__ int    rix[256];
    const int tid = threadIdx.x;
    const int n   = *cnt;
    for (int fi = blockIdx.x; fi < n; fi += gridDim.x) {
        int t = tlist[fi];
        if (tid < D4) xls[tid] = x4[(size_t)t * D4 + tid];
        __syncthreads();
        double bv = INFINITY; int bi = 0x7fffffff;
        for (int k = tid; k < K; k += 256) {
            const float4* cr = cb4 + (size_t)ridx[k] * D4;
            double s = 0.0, cc = 0.0;
            #pragma unroll 4
            for (int d = 0; d < D4; ++d) {
                float4 cv = cr[d], xv = xls[d];
                s  = fma((double)cv.x, (double)xv.x, s);
                s  = fma((double)cv.y, (double)xv.y, s);
                s  = fma((double)cv.z, (double)xv.z, s);
                s  = fma((double)cv.w, (double)xv.w, s);
                cc = fma((double)cv.x, (double)cv.x, cc);
                cc = fma((double)cv.y, (double)cv.y, cc);
                cc = fma((double)cv.z, (double)cv.z, cc);
                cc = fma((double)cv.w, (double)cv.w, cc);
            }
            double sc = cc - 2.0 * s;
            if (sc < bv || (sc == bv && k < bi)) { bv = sc; bi = k; }
        }
        rv[tid] = bv; rix[tid] = bi;
        __syncthreads();
        for (int st = 128; st; st >>= 1) {
            if (tid < st) {
                double u = rv[tid + st]; int ui = rix[tid + st];
                if (u < rv[tid] || (u == rv[tid] && ui < rix[tid])) {
                    rv[tid] = u; rix[tid] = ui;
                }
            }
            __syncthreads();
        }
        if (tid == 0) gidx[t] = ridx[rix[0]];
        __syncthreads();
    }
}

// ---------------------------------------------------------------------------
// k3: gather codebook row per token, write tokens + float index + sq-err sum.
__global__ __launch_bounds__(256)
void k3_gather(const float4* __restrict__ x4, const float4* __restrict__ cb4,
               const int* __restrict__ gidx, float4* __restrict__ out_tok,
               float* __restrict__ out_idx, float* __restrict__ tok_loss,
               int Ntok) {
    int t    = (int)(blockIdx.x * 4 + (threadIdx.x >> 6));
    int lane = threadIdx.x & 63;
    if (t >= Ntok) return;
    int g = gidx[t];
    float4 cv = cb4[(size_t)g * D4 + lane];
    float4 xv = x4[(size_t)t * D4 + lane];
    out_tok[(size_t)t * D4 + lane] = cv;
    if (lane == 0) out_idx[t] = (float)g;
    float dx = cv.x - xv.x, dy = cv.y - xv.y, dz = cv.z - xv.z, dw = cv.w - xv.w;
    float s = dx * dx + dy * dy + dz * dz + dw * dw;
    #pragma unroll
    for (int off = 32; off; off >>= 1) s += __shfl_xor(s, off, 64);
    if (lane == 0) tok_loss[t] = s;
}

// ---------------------------------------------------------------------------
// k4: deterministic fixed-order loss mean.
__global__ __launch_bounds__(256)
void k4_loss(const float* __restrict__ tok_loss, float* __restrict__ out_loss,
             int Ntok, double inv_total) {
    __shared__ double sm[256];
    double s = 0.0;
    for (int i = threadIdx.x; i < Ntok; i += 256) s += (double)tok_loss[i];
    sm[threadIdx.x] = s;
    __syncthreads();
    for (int st = 128; st; st >>= 1) {
        if ((int)threadIdx.x < st) sm[threadIdx.x] += sm[threadIdx.x + st];
        __syncthreads();
    }
    if (threadIdx.x == 0) *out_loss = (float)(sm[0] * inv_total);
}

// ---------------------------------------------------------------------------
extern "C" void kernel_launch(void* const* d_in, const int* in_sizes, int n_in,
                              void* d_out, int out_size, void* d_ws, size_t ws_size,
                              hipStream_t stream) {
    const float* x    = (const float*)d_in[0];
    const float* cb   = (const float*)d_in[1];
    const int*   ridx = (const int*)d_in[2];

    const int Ntok  = in_sizes[0] / D;          // 16384
    const int K     = in_sizes[2];              // 3686
    const int kpad  = KB * KTILES * TN;         // 4096
    const int kspan = KTILES * TN;              // 1024

    float* out      = (float*)d_out;
    float* out_loss = out + (size_t)Ntok * D;
    float* out_idx  = out + (size_t)Ntok * D + 1;

    // ws layout
    char* w = (char*)d_ws;
    auto up = [](size_t v) { return (v + 255) & ~(size_t)255; };
    float* c2    = (float*)w;  w += up((size_t)kpad * 4);
    float* pb1   = (float*)w;  w += up((size_t)KB * Ntok * 4);
    float* pb2   = (float*)w;  w += up((size_t)KB * Ntok * 4);
    int*   pbi   = (int*)w;    w += up((size_t)KB * Ntok * 4);
    int*   gidx  = (int*)w;    w += up((size_t)Ntok * 4);
    int*   tlist = (int*)w;    w += up((size_t)Ntok * 4);
    float* tl    = (float*)w;  w += up((size_t)Ntok * 4);
    int*   cnt   = (int*)w;

    const float4* x4  = (const float4*)x;
    const float4* cb4 = (const float4*)cb;

    hipMemsetAsync(cnt, 0, 4, stream);

    k0_c2<<<dim3(kpad / 4), dim3(256), 0, stream>>>(cb4, ridx, c2, K, kpad);

    k1_argmin<<<dim3(Ntok / TM, KB), dim3(256), 0, stream>>>(
        x4, cb4, ridx, c2, pb1, pb2, pbi, Ntok, K, kspan);

    k2_combine<<<dim3((Ntok + 255) / 256), dim3(256), 0, stream>>>(
        pb1, pb2, pbi, ridx, gidx, tlist, cnt, Ntok);

    k_recheck<<<dim3(256), dim3(256), 0, stream>>>(
        x4, cb4, ridx, tlist, cnt, gidx, K);

    k3_gather<<<dim3((Ntok + 3) / 4), dim3(256), 0, stream>>>(
        x4, cb4, gidx, (float4*)out, out_idx, tl, Ntok);

    k4_loss<<<dim3(1), dim3(256), 0, stream>>>(
        tl, out_loss, Ntok, 1.0 / ((double)Ntok * (double)D));
}

// Round 3
// 468.843 us; speedup vs baseline: 2.0813x; 1.3583x over previous
//
#include <hip/hip_runtime.h>
#include <math.h>

// Problem geometry: D=256 fixed; N, K from in_sizes.
#define D      256
#define D4     64
#define TAU    6.0e-3f   // near-tie margin; score error bound ~2e-3 < TAU/2

// ---- MFMA-path geometry ----
#define KPAD    4096     // padded subsampled-codebook size
#define NSPLIT  8        // K splits (== #XCDs; kb = blockIdx.x & 7)
#define KSPAN   512      // entries per split
#define TNE     256      // entry tile per block iteration
#define TMTOK   128      // token tile per block
#define KPK     768      // packed K'' = 3 slices of 256 (hh, hl, lh)
#define BK      64       // staged K'' chunk
#define NCHUNK  (KPK / BK)   // 12

typedef short bf16x8 __attribute__((ext_vector_type(8)));
typedef float f32x16 __attribute__((ext_vector_type(16)));

#define GLD16(g, l) __builtin_amdgcn_global_load_lds( \
    (const __attribute__((address_space(1))) void*)(g), \
    (__attribute__((address_space(3))) void*)(l), 16, 0, 0)

__device__ inline ushort f2bf_rn(float f) {           // RNE f32 -> bf16 bits
    unsigned u = __float_as_uint(f);
    unsigned r = (u + 0x7fffu + ((u >> 16) & 1u)) >> 16;
    return (ushort)r;
}
__device__ inline float bf2f(ushort u) { return __uint_as_float(((unsigned)u) << 16); }
__device__ inline f32x16 zero16() {
    f32x16 z = {0,0,0,0,0,0,0,0,0,0,0,0,0,0,0,0};
    return z;
}

// ---------------------------------------------------------------------------
// p0: xpack[t][512] = [ bf16hi(x_t) (256) | bf16lo(x_t) (256) ]. One wave/token.
__global__ __launch_bounds__(256)
void p0_xpack(const float4* __restrict__ x4, ushort* __restrict__ xp, int Ntok) {
    int t    = (int)(blockIdx.x * 4 + (threadIdx.x >> 6));
    int lane = threadIdx.x & 63;
    if (t >= Ntok) return;
    float4 v = x4[(size_t)t * D4 + lane];
    float f[4] = {v.x, v.y, v.z, v.w};
    ushort4 h, lo;
    ushort* hp = &h.x; ushort* lp = &lo.x;
    #pragma unroll
    for (int i = 0; i < 4; ++i) {
        ushort hb = f2bf_rn(f[i]);
        hp[i] = hb;
        lp[i] = f2bf_rn(f[i] - bf2f(hb));
    }
    *(ushort4*)&xp[(size_t)t * 512 + 4 * lane]       = h;
    *(ushort4*)&xp[(size_t)t * 512 + 256 + 4 * lane] = lo;
}

// ---------------------------------------------------------------------------
// p1: cpack[k][512] = [ bf16hi(sub_k) | bf16lo(sub_k) ] (zeros for pads) and
// c2[k] = ||sub_k||^2 exact-f64 (f32 out, +inf for pads). One wave/entry.
__global__ __launch_bounds__(256)
void p1_cpack(const float4* __restrict__ cb4, const int* __restrict__ ridx,
              ushort* __restrict__ cp, float* __restrict__ c2, int K) {
    int k    = (int)(blockIdx.x * 4 + (threadIdx.x >> 6));
    int lane = threadIdx.x & 63;
    if (k >= KPAD) return;
    ushort4 h, lo;
    ushort* hp = &h.x; ushort* lp = &lo.x;
    double s = 0.0;
    if (k < K) {
        int row = ridx[k];
        float4 v = cb4[(size_t)row * D4 + lane];
        float f[4] = {v.x, v.y, v.z, v.w};
        #pragma unroll
        for (int i = 0; i < 4; ++i) {
            ushort hb = f2bf_rn(f[i]);
            hp[i] = hb;
            lp[i] = f2bf_rn(f[i] - bf2f(hb));
            s = fma((double)f[i], (double)f[i], s);
        }
    } else {
        hp[0]=hp[1]=hp[2]=hp[3]=0; lp[0]=lp[1]=lp[2]=lp[3]=0;
    }
    *(ushort4*)&cp[(size_t)k * 512 + 4 * lane]       = h;
    *(ushort4*)&cp[(size_t)k * 512 + 256 + 4 * lane] = lo;
    #pragma unroll
    for (int off = 32; off; off >>= 1) s += __shfl_xor(s, off, 64);
    if (lane == 0) c2[k] = (k < K) ? (float)s : INFINITY;
}

// ---------------------------------------------------------------------------
// k1_mfma: per (token-tile, split): score = c2 - 2*dot3(x, c) via bf16 MFMA
// over packed K''=768. LDS stored in fragment-linear order => conflict-free
// ds_read_b128 at base + lane*16; staged with global_load_lds width 16.
// Tracks per-token (best, 2nd, idx); partials -> pb*.
__global__ __launch_bounds__(256, 2)
void k1_mfma(const ushort* __restrict__ xp, const ushort* __restrict__ cp,
             const float* __restrict__ c2,
             float* __restrict__ pb1, float* __restrict__ pb2,
             int* __restrict__ pbi, int Ntok) {
    __shared__ __align__(16) ushort ldsA[32 * 512];  // 32 KiB: 32 frag-groups
    __shared__ __align__(16) ushort ldsB[16 * 512];  // 16 KiB: 16 frag-groups
    __shared__ float c2t[TNE];                       // 1 KiB

    const int tid  = threadIdx.x;
    const int w    = tid >> 6;
    const int lane = tid & 63;
    const int we   = w >> 1;          // entry half (0..1): 128 entries
    const int wn   = w & 1;           // token half (0..1): 64 tokens
    const int hi   = lane >> 5;
    const int l31  = lane & 31;

    const int kb  = blockIdx.x & 7;
    const int m0  = (int)(blockIdx.x >> 3) * TMTOK;
    const int e0s = kb * KSPAN;

    float b1[2] = {INFINITY, INFINITY}, b2[2] = {INFINITY, INFINITY};
    int   bi[2] = {0, 0};

    for (int tile = 0; tile < KSPAN / TNE; ++tile) {     // 2 entry tiles
        const int e0 = e0s + tile * TNE;
        __syncthreads();                                  // prev epilogue done
        c2t[tid] = c2[e0 + tid];                          // TNE == blockDim

        f32x16 acc[4][2];
        #pragma unroll
        for (int mt = 0; mt < 4; ++mt)
            #pragma unroll
            for (int nt = 0; nt < 2; ++nt) acc[mt][nt] = zero16();

        for (int chunk = 0; chunk < NCHUNK; ++chunk) {
            const int kk0 = chunk * BK;
            __syncthreads();                              // prev frag reads done
            // stage A (entries): wave w covers frag-groups p = w*8 + j
            #pragma unroll
            for (int j = 0; j < 8; ++j) {
                int p = w * 8 + j;
                int kc = p >> 3, g = p & 7;
                int krow = e0 + g * 32 + l31;
                int kcol = kk0 + kc * 16 + hi * 8;        // packed k''
                int slice = kcol >> 8;                    // 0:hh 1:hl 2:lh
                int srck  = ((slice == 1) ? 256 : 0) + (kcol & 255);  // c: hi,lo,hi
                GLD16(cp + (size_t)krow * 512 + srck, &ldsA[p * 512]);
            }
            // stage B (tokens): q = w*4 + j
            #pragma unroll
            for (int j = 0; j < 4; ++j) {
                int q = w * 4 + j;
                int kc = q >> 2, g = q & 3;
                int trow = m0 + g * 32 + l31;
                int kcol = kk0 + kc * 16 + hi * 8;
                int slice = kcol >> 8;
                int srck  = ((slice == 2) ? 256 : 0) + (kcol & 255);  // x: hi,hi,lo
                GLD16(xp + (size_t)trow * 512 + srck, &ldsB[q * 512]);
            }
            __syncthreads();                              // vmcnt drained @barrier

            #pragma unroll
            for (int kc = 0; kc < 4; ++kc) {
                bf16x8 af[4], bfr[2];
                #pragma unroll
                for (int mt = 0; mt < 4; ++mt)
                    af[mt] = *(const bf16x8*)&ldsA[(kc * 8 + we * 4 + mt) * 512 + lane * 8];
                #pragma unroll
                for (int nt = 0; nt < 2; ++nt)
                    bfr[nt] = *(const bf16x8*)&ldsB[(kc * 4 + wn * 2 + nt) * 512 + lane * 8];
                #pragma unroll
                for (int mt = 0; mt < 4; ++mt)
                    #pragma unroll
                    for (int nt = 0; nt < 2; ++nt)
                        acc[mt][nt] = __builtin_amdgcn_mfma_f32_32x32x16_bf16(
                            af[mt], bfr[nt], acc[mt][nt], 0, 0, 0);
            }
        }

        // epilogue: scores + branchless top-2 (lexicographic tie-break)
        #pragma unroll
        for (int nt = 0; nt < 2; ++nt)
            #pragma unroll
            for (int mt = 0; mt < 4; ++mt)
                #pragma unroll
                for (int r = 0; r < 16; ++r) {
                    int rl = we * 128 + mt * 32 + (r & 3) + 8 * (r >> 2) + 4 * hi;
                    float sc = fmaf(-2.f, acc[mt][nt][r], c2t[rl]);
                    int   k  = e0 + rl;
                    bool better = (sc < b1[nt]) || (sc == b1[nt] && k < bi[nt]);
                    float nb2 = better ? b1[nt] : fminf(b2[nt], sc);
                    b1[nt] = better ? sc : b1[nt];
                    bi[nt] = better ? k  : bi[nt];
                    b2[nt] = nb2;
                }
    }

    // merge lane <-> lane^32 (complementary rows, same token col)
    #pragma unroll
    for (int nt = 0; nt < 2; ++nt) {
        float o1 = __shfl_xor(b1[nt], 32, 64);
        float o2 = __shfl_xor(b2[nt], 32, 64);
        int   oi = __shfl_xor(bi[nt], 32, 64);
        if (o1 < b1[nt] || (o1 == b1[nt] && oi < bi[nt])) {
            b2[nt] = fminf(b1[nt], o2); b1[nt] = o1; bi[nt] = oi;
        } else b2[nt] = fminf(b2[nt], o1);
    }

    __syncthreads();                                      // all frag reads done
    float* s1 = (float*)ldsA;           // [we][128 tokens]
    float* s2 = s1 + 256;
    int*   si = (int*)(s2 + 256);
    if (hi == 0) {
        #pragma unroll
        for (int nt = 0; nt < 2; ++nt) {
            int tl = wn * 64 + nt * 32 + l31;
            s1[we * 128 + tl] = b1[nt];
            s2[we * 128 + tl] = b2[nt];
            si[we * 128 + tl] = bi[nt];
        }
    }
    __syncthreads();
    if (tid < TMTOK) {
        float v1 = s1[tid], v2 = s2[tid]; int vi = si[tid];
        float u1 = s1[128 + tid], u2 = s2[128 + tid]; int ui = si[128 + tid];
        if (u1 < v1 || (u1 == v1 && ui < vi)) { v2 = fminf(v1, u2); v1 = u1; vi = ui; }
        else                                  { v2 = fminf(v2, u1); }
        size_t o = (size_t)kb * Ntok + m0 + tid;
        pb1[o] = v1; pb2[o] = v2; pbi[o] = vi;
    }
}

// ---------------------------------------------------------------------------
// ---- f32 fallback path (round-2, proven) — used only if ws too small ----
#define FTM 128
#define FTN 128
#define FKB 4
#define FKTILES 8

__global__ __launch_bounds__(256)
void k0_c2(const float4* __restrict__ cb4, const int* __restrict__ ridx,
           float* __restrict__ c2, int K, int kpad) {
    int k    = (int)(blockIdx.x * 4 + (threadIdx.x >> 6));
    int lane = threadIdx.x & 63;
    if (k >= kpad) return;
    double s = 0.0;
    if (k < K) {
        int row = ridx[k];
        float4 v = cb4[(size_t)row * D4 + lane];
        s = (double)v.x * v.x + (double)v.y * v.y
          + (double)v.z * v.z + (double)v.w * v.w;
    }
    #pragma unroll
    for (int off = 32; off; off >>= 1) s += __shfl_xor(s, off, 64);
    if (lane == 0) c2[k] = (k < K) ? (float)s : INFINITY;
}

__global__ __launch_bounds__(256, 2)
void fk1_argmin(const float4* __restrict__ x4, const float4* __restrict__ cb4,
                const int* __restrict__ ridx, const float* __restrict__ c2,
                float* __restrict__ pb1, float* __restrict__ pb2,
                int* __restrict__ pbi, int Ntok, int K, int kspan) {
    __shared__ float4 xs4[FTM * 16];
    __shared__ float4 cs4[FTN * 16];
    __shared__ float  c2_t[FTN];
    const int tid = threadIdx.x;
    const int r = tid >> 4, c = tid & 15;
    const int m0 = blockIdx.x * FTM;
    const int kbase0 = blockIdx.y * kspan;
    float b1[8], b2[8]; int bi[8];
    #pragma unroll
    for (int i = 0; i < 8; ++i) { b1[i] = INFINITY; b2[i] = INFINITY; bi[i] = 0; }
    for (int t = 0; t < FKTILES; ++t) {
        const int kbase = kbase0 + t * FTN;
        if (kbase >= K) break;
        __syncthreads();
        if (tid < FTN) c2_t[tid] = c2[kbase + tid];
        int cidx[8];
        #pragma unroll
        for (int q = 0; q < 8; ++q) {
            int k = kbase + 16 * q + r;
            cidx[q] = ridx[(k < K) ? k : 0];
        }
        float acc[8][8];
        #pragma unroll
        for (int i = 0; i < 8; ++i)
            #pragma unroll
            for (int j = 0; j < 8; ++j) acc[i][j] = 0.f;
        for (int ch = 0; ch < 4; ++ch) {
            __syncthreads();
            #pragma unroll
            for (int q = 0; q < 8; ++q) {
                int row = 16 * q + r;
                int p   = c ^ (row & 7);
                xs4[row * 16 + p] = x4[(size_t)(m0 + row) * D4 + ch * 16 + c];
                cs4[row * 16 + p] = cb4[(size_t)cidx[q] * D4 + ch * 16 + c];
            }
            __syncthreads();
            #pragma unroll 2
            for (int f = 0; f < 16; ++f) {
                float4 xf[8];
                #pragma unroll
                for (int i = 0; i < 8; ++i) xf[i] = xs4[(8 * r + i) * 16 + (f ^ i)];
                #pragma unroll
                for (int j = 0; j < 8; ++j) {
                    float4 cf = cs4[(c + 16 * j) * 16 + (f ^ (c & 7))];
                    #pragma unroll
                    for (int i = 0; i < 8; ++i) {
                        acc[i][j] = fmaf(xf[i].x, cf.x, acc[i][j]);
                        acc[i][j] = fmaf(xf[i].y, cf.y, acc[i][j]);
                        acc[i][j] = fmaf(xf[i].z, cf.z, acc[i][j]);
                        acc[i][j] = fmaf(xf[i].w, cf.w, acc[i][j]);
                    }
                }
            }
        }
        #pragma unroll
        for (int j = 0; j < 8; ++j) {
            float c2v = c2_t[c + 16 * j];
            int   k   = kbase + c + 16 * j;
            #pragma unroll
            for (int i = 0; i < 8; ++i) {
                float sc = fmaf(-2.f, acc[i][j], c2v);
                if (sc < b1[i]) { b2[i] = b1[i]; b1[i] = sc; bi[i] = k; }
                else            { b2[i] = fminf(b2[i], sc); }
            }
        }
    }
    __syncthreads();
    float* s1 = (float*)xs4;
    float* s2 = s1 + FTM * 16;
    int*   si = (int*)cs4;
    #pragma unroll
    for (int i = 0; i < 8; ++i) {
        int row = 8 * r + i;
        s1[row * 16 + c] = b1[i]; s2[row * 16 + c] = b2[i]; si[row * 16 + c] = bi[i];
    }
    __syncthreads();
    if (tid < FTM) {
        float v1 = s1[tid * 16], v2 = s2[tid * 16];
        int   vi = si[tid * 16];
        #pragma unroll
        for (int cc = 1; cc < 16; ++cc) {
            float u1 = s1[tid * 16 + cc], u2 = s2[tid * 16 + cc];
            int   ui = si[tid * 16 + cc];
            if (u1 < v1 || (u1 == v1 && ui < vi)) { v2 = fminf(v1, u2); v1 = u1; vi = ui; }
            else                                  { v2 = fminf(v2, u1); }
        }
        size_t o = (size_t)blockIdx.y * Ntok + m0 + tid;
        pb1[o] = v1; pb2[o] = v2; pbi[o] = vi;
    }
}

// ---------------------------------------------------------------------------
// shared epilogue kernels
__global__ __launch_bounds__(256)
void k2_combine(const float* __restrict__ pb1, const float* __restrict__ pb2,
                const int* __restrict__ pbi, const int* __restrict__ ridx,
                int* __restrict__ gidx, int* __restrict__ tlist,
                int* __restrict__ cnt, int Ntok, int nsplit) {
    int t = blockIdx.x * 256 + threadIdx.x;
    if (t >= Ntok) return;
    float v1 = INFINITY, v2 = INFINITY; int vi = 0x7fffffff;
    for (int kb = 0; kb < nsplit; ++kb) {
        size_t o = (size_t)kb * Ntok + t;
        float u1 = pb1[o], u2 = pb2[o]; int ui = pbi[o];
        if (u1 < v1 || (u1 == v1 && ui < vi)) { v2 = fminf(v1, u2); v1 = u1; vi = ui; }
        else                                  { v2 = fminf(v2, u1); }
    }
    gidx[t] = ridx[vi];
    if (v2 - v1 < TAU) {
        int pos = atomicAdd(cnt, 1);
        tlist[pos] = t;
    }
}

__global__ __launch_bounds__(256)
void k_recheck(const float4* __restrict__ x4, const float4* __restrict__ cb4,
               const int* __restrict__ ridx, const int* __restrict__ tlist,
               const int* __restrict__ cnt, int* __restrict__ gidx, int K) {
    __shared__ float4 xls[D4];
    __shared__ double rv[256];
    __shared__ int    rix[256];
    const int tid = threadIdx.x;
    const int n   = *cnt;
    for (int fi = blockIdx.x; fi < n; fi += gridDim.x) {
        int t = tlist[fi];
        if (tid < D4) xls[tid] = x4[(size_t)t * D4 + tid];
        __syncthreads();
        double bv = INFINITY; int bi = 0x7fffffff;
        for (int k = tid; k < K; k += 256) {
            const float4* cr = cb4 + (size_t)ridx[k] * D4;
            double s = 0.0, cc = 0.0;
            #pragma unroll 4
            for (int d = 0; d < D4; ++d) {
                float4 cv = cr[d], xv = xls[d];
                s  = fma((double)cv.x, (double)xv.x, s);
                s  = fma((double)cv.y, (double)xv.y, s);
                s  = fma((double)cv.z, (double)xv.z, s);
                s  = fma((double)cv.w, (double)xv.w, s);
                cc = fma((double)cv.x, (double)cv.x, cc);
                cc = fma((double)cv.y, (double)cv.y, cc);
                cc = fma((double)cv.z, (double)cv.z, cc);
                cc = fma((double)cv.w, (double)cv.w, cc);
            }
            double sc = cc - 2.0 * s;
            if (sc < bv || (sc == bv && k < bi)) { bv = sc; bi = k; }
        }
        rv[tid] = bv; rix[tid] = bi;
        __syncthreads();
        for (int st = 128; st; st >>= 1) {
            if (tid < st) {
                double u = rv[tid + st]; int ui = rix[tid + st];
                if (u < rv[tid] || (u == rv[tid] && ui < rix[tid])) {
                    rv[tid] = u; rix[tid] = ui;
                }
            }
            __syncthreads();
        }
        if (tid == 0) gidx[t] = ridx[rix[0]];
        __syncthreads();
    }
}

__global__ __launch_bounds__(256)
void k3_gather(const float4* __restrict__ x4, const float4* __restrict__ cb4,
               const int* __restrict__ gidx, float4* __restrict__ out_tok,
               float* __restrict__ out_idx, float* __restrict__ tok_loss,
               int Ntok) {
    int t    = (int)(blockIdx.x * 4 + (threadIdx.x >> 6));
    int lane = threadIdx.x & 63;
    if (t >= Ntok) return;
    int g = gidx[t];
    float4 cv = cb4[(size_t)g * D4 + lane];
    float4 xv = x4[(size_t)t * D4 + lane];
    out_tok[(size_t)t * D4 + lane] = cv;
    if (lane == 0) out_idx[t] = (float)g;
    float dx = cv.x - xv.x, dy = cv.y - xv.y, dz = cv.z - xv.z, dw = cv.w - xv.w;
    float s = dx * dx + dy * dy + dz * dz + dw * dw;
    #pragma unroll
    for (int off = 32; off; off >>= 1) s += __shfl_xor(s, off, 64);
    if (lane == 0) tok_loss[t] = s;
}

__global__ __launch_bounds__(256)
void k4_loss(const float* __restrict__ tok_loss, float* __restrict__ out_loss,
             int Ntok, double inv_total) {
    __shared__ double sm[256];
    double s = 0.0;
    for (int i = threadIdx.x; i < Ntok; i += 256) s += (double)tok_loss[i];
    sm[threadIdx.x] = s;
    __syncthreads();
    for (int st = 128; st; st >>= 1) {
        if ((int)threadIdx.x < st) sm[threadIdx.x] += sm[threadIdx.x + st];
        __syncthreads();
    }
    if (threadIdx.x == 0) *out_loss = (float)(sm[0] * inv_total);
}

// ---------------------------------------------------------------------------
extern "C" void kernel_launch(void* const* d_in, const int* in_sizes, int n_in,
                              void* d_out, int out_size, void* d_ws, size_t ws_size,
                              hipStream_t stream) {
    const float* x    = (const float*)d_in[0];
    const float* cb   = (const float*)d_in[1];
    const int*   ridx = (const int*)d_in[2];

    const int Ntok = in_sizes[0] / D;          // 16384
    const int K    = in_sizes[2];              // 3686

    float* out      = (float*)d_out;
    float* out_loss = out + (size_t)Ntok * D;
    float* out_idx  = out + (size_t)Ntok * D + 1;

    const float4* x4  = (const float4*)x;
    const float4* cb4 = (const float4*)cb;

    auto up = [](size_t v) { return (v + 255) & ~(size_t)255; };

    // MFMA-path ws need: cpack + c2 + pb*(8 splits) + gidx/tlist/tl + cnt
    size_t need = up((size_t)KPAD * 512 * 2) + up((size_t)KPAD * 4)
                + 3 * up((size_t)NSPLIT * Ntok * 4) + 3 * up((size_t)Ntok * 4) + 256;

    if (ws_size >= need) {
        // ---------------- MFMA path ----------------
        char* w = (char*)d_ws;
        ushort* cpack = (ushort*)w; w += up((size_t)KPAD * 512 * 2);
        float*  c2    = (float*)w;  w += up((size_t)KPAD * 4);
        float*  pb1   = (float*)w;  w += up((size_t)NSPLIT * Ntok * 4);
        float*  pb2   = (float*)w;  w += up((size_t)NSPLIT * Ntok * 4);
        int*    pbi   = (int*)w;    w += up((size_t)NSPLIT * Ntok * 4);
        int*    gidx  = (int*)w;    w += up((size_t)Ntok * 4);
        int*    tlist = (int*)w;    w += up((size_t)Ntok * 4);
        float*  tl    = (float*)w;  w += up((size_t)Ntok * 4);
        int*    cnt   = (int*)w;

        ushort* xpack = (ushort*)d_out;   // 16.78 MB: exact fit in out_tok region

        hipMemsetAsync(cnt, 0, 4, stream);
        p0_xpack<<<dim3(Ntok / 4), dim3(256), 0, stream>>>(x4, xpack, Ntok);
        p1_cpack<<<dim3(KPAD / 4), dim3(256), 0, stream>>>(cb4, ridx, cpack, c2, K);
        k1_mfma<<<dim3((Ntok / TMTOK) * NSPLIT), dim3(256), 0, stream>>>(
            xpack, cpack, c2, pb1, pb2, pbi, Ntok);
        k2_combine<<<dim3((Ntok + 255) / 256), dim3(256), 0, stream>>>(
            pb1, pb2, pbi, ridx, gidx, tlist, cnt, Ntok, NSPLIT);
        k_recheck<<<dim3(256), dim3(256), 0, stream>>>(
            x4, cb4, ridx, tlist, cnt, gidx, K);
        k3_gather<<<dim3((Ntok + 3) / 4), dim3(256), 0, stream>>>(
            x4, cb4, gidx, (float4*)out, out_idx, tl, Ntok);
        k4_loss<<<dim3(1), dim3(256), 0, stream>>>(
            tl, out_loss, Ntok, 1.0 / ((double)Ntok * (double)D));
    } else {
        // ---------------- f32 fallback (round-2 proven) ----------------
        const int kpad  = 4096;
        const int kspan = 1024;
        char* w = (char*)d_ws;
        float* c2    = (float*)w;  w += up((size_t)kpad * 4);
        float* pb1   = (float*)w;  w += up((size_t)FKB * Ntok * 4);
        float* pb2   = (float*)w;  w += up((size_t)FKB * Ntok * 4);
        int*   pbi   = (int*)w;    w += up((size_t)FKB * Ntok * 4);
        int*   gidx  = (int*)w;    w += up((size_t)Ntok * 4);
        int*   tlist = (int*)w;    w += up((size_t)Ntok * 4);
        float* tl    = (float*)w;  w += up((size_t)Ntok * 4);
        int*   cnt   = (int*)w;

        hipMemsetAsync(cnt, 0, 4, stream);
        k0_c2<<<dim3(kpad / 4), dim3(256), 0, stream>>>(cb4, ridx, c2, K, kpad);
        fk1_argmin<<<dim3(Ntok / FTM, FKB), dim3(256), 0, stream>>>(
            x4, cb4, ridx, c2, pb1, pb2, pbi, Ntok, K, kspan);
        k2_combine<<<dim3((Ntok + 255) / 256), dim3(256), 0, stream>>>(
            pb1, pb2, pbi, ridx, gidx, tlist, cnt, Ntok, FKB);
        k_recheck<<<dim3(256), dim3(256), 0, stream>>>(
            x4, cb4, ridx, tlist, cnt, gidx, K);
        k3_gather<<<dim3((Ntok + 3) / 4), dim3(256), 0, stream>>>(
            x4, cb4, gidx, (float4*)out, out_idx, tl, Ntok);
        k4_loss<<<dim3(1), dim3(256), 0, stream>>>(
            tl, out_loss, Ntok, 1.0 / ((double)Ntok * (double)D));
    }
}